// Round 1
// baseline (1110.191 us; speedup 1.0000x reference)
//
#include <hip/hip_runtime.h>

// PairMixing: y_L[n,k,f] = sum_{triples (l1,l2,L)} (rbf[n,:]·W_t[f,:]) *
//                          sum_{i,j} cg_t[i,j,k] * x1_{l1}[n,i,f] * x2_{l2}[n,j,f]
// N=60000, F=128, B=32, 15 triples.
//
// Strategy: one thread per (n,f) element stream; block = 256 threads =
// 128 f-lanes x 2 n-halves, NB=8 pairs per block (7500 blocks).
// cg and rbf are wave-uniform -> read at uniform addresses so they compile to
// s_load and feed v_fmac as SGPR operands (no LDS streaming, no VMEM cost).
// coeff (15 triples x 4 n) kept in VGPRs; phase 2 in two passes of 2 n's to
// bound register pressure.

#define NPAIR 60000
#define NB    8
#define Y1OFF (NPAIR * 128)        // 7,680,000
#define Y2OFF (NPAIR * 128 * 4)    // 30,720,000

template<int D1, int D2, int DK>
__device__ __forceinline__ void triple_acc(
    const float* __restrict__ cg,
    const float (&a)[D1][2], const float (&b)[D2][2],
    float cf0, float cf1, float (&y)[DK][2])
{
    float tp[DK][2];
#pragma unroll
    for (int k = 0; k < DK; ++k) { tp[k][0] = 0.f; tp[k][1] = 0.f; }
#pragma unroll
    for (int i = 0; i < D1; ++i) {
#pragma unroll
        for (int j = 0; j < D2; ++j) {
#pragma unroll
            for (int nn = 0; nn < 2; ++nn) {
                const float prod = a[i][nn] * b[j][nn];
#pragma unroll
                for (int k = 0; k < DK; ++k) {
                    // cg[...] is a uniform address -> s_load; SGPR operand in fma
                    tp[k][nn] = fmaf(cg[(i * D2 + j) * DK + k], prod, tp[k][nn]);
                }
            }
        }
    }
#pragma unroll
    for (int k = 0; k < DK; ++k) {
        y[k][0] = fmaf(cf0, tp[k][0], y[k][0]);
        y[k][1] = fmaf(cf1, tp[k][1], y[k][1]);
    }
}

__device__ __forceinline__ void coeff_t(
    const float* __restrict__ Wt, const float* __restrict__ rbfp,
    int f, float (&cfo)[4])
{
    // thread f reads its own W row (32 floats) as 8x float4 (L1/L2-resident,
    // amortized over the block's 8 n's); rbf values are wave-uniform s_loads.
    const float4* wp = (const float4*)(Wt + ((size_t)f << 5));
    float wv[32];
#pragma unroll
    for (int q = 0; q < 8; ++q) {
        const float4 v = wp[q];
        wv[4 * q + 0] = v.x; wv[4 * q + 1] = v.y;
        wv[4 * q + 2] = v.z; wv[4 * q + 3] = v.w;
    }
#pragma unroll
    for (int nn = 0; nn < 4; ++nn) {
        float acc = 0.f;
#pragma unroll
        for (int b = 0; b < 32; ++b)
            acc = fmaf(rbfp[nn * 32 + b], wv[b], acc);
        cfo[nn] = acc;
    }
}

__global__ __launch_bounds__(256, 3) void pair_mixing_kernel(
    const float* __restrict__ x1_0, const float* __restrict__ x1_1, const float* __restrict__ x1_2,
    const float* __restrict__ x2_0, const float* __restrict__ x2_1, const float* __restrict__ x2_2,
    const float* __restrict__ rbf,
    const float* __restrict__ cg0,  const float* __restrict__ cg1,  const float* __restrict__ cg2,
    const float* __restrict__ cg3,  const float* __restrict__ cg4,  const float* __restrict__ cg5,
    const float* __restrict__ cg6,  const float* __restrict__ cg7,  const float* __restrict__ cg8,
    const float* __restrict__ cg9,  const float* __restrict__ cg10, const float* __restrict__ cg11,
    const float* __restrict__ cg12, const float* __restrict__ cg13, const float* __restrict__ cg14,
    const float* __restrict__ W0,  const float* __restrict__ W1,  const float* __restrict__ W2,
    const float* __restrict__ W3,  const float* __restrict__ W4,  const float* __restrict__ W5,
    const float* __restrict__ W6,  const float* __restrict__ W7,  const float* __restrict__ W8,
    const float* __restrict__ W9,  const float* __restrict__ W10, const float* __restrict__ W11,
    const float* __restrict__ W12, const float* __restrict__ W13, const float* __restrict__ W14,
    float* __restrict__ out)
{
    const int tid = threadIdx.x;
    const int f   = tid & 127;
    const int sub = tid >> 7;                     // 0 or 1: which 4-n half
    const int nbt = blockIdx.x * NB + sub * 4;    // first n for this thread
    // uniform per wave (waves 0,1 -> sub 0; waves 2,3 -> sub 1)
    const int nbu = __builtin_amdgcn_readfirstlane(nbt);
    const float* rbfp = rbf + ((size_t)nbu << 5); // uniform base -> s_load path

    // ---- phase 1: coeff[t][nn] = rbf[n,:] . W_t[f,:] ----
    float cf[15][4];
    coeff_t(W0,  rbfp, f, cf[0]);
    coeff_t(W1,  rbfp, f, cf[1]);
    coeff_t(W2,  rbfp, f, cf[2]);
    coeff_t(W3,  rbfp, f, cf[3]);
    coeff_t(W4,  rbfp, f, cf[4]);
    coeff_t(W5,  rbfp, f, cf[5]);
    coeff_t(W6,  rbfp, f, cf[6]);
    coeff_t(W7,  rbfp, f, cf[7]);
    coeff_t(W8,  rbfp, f, cf[8]);
    coeff_t(W9,  rbfp, f, cf[9]);
    coeff_t(W10, rbfp, f, cf[10]);
    coeff_t(W11, rbfp, f, cf[11]);
    coeff_t(W12, rbfp, f, cf[12]);
    coeff_t(W13, rbfp, f, cf[13]);
    coeff_t(W14, rbfp, f, cf[14]);

    // ---- phase 2: tensor products, two passes of 2 n's each ----
#pragma unroll
    for (int pass = 0; pass < 2; ++pass) {
        const int nb = nbt + pass * 2;

        float a0[1][2], a1[3][2], a2[5][2];
        float c0[1][2], c1[3][2], c2[5][2];
#pragma unroll
        for (int nn = 0; nn < 2; ++nn) {
            const int n = nb + nn;
            a0[0][nn] = x1_0[n * 128 + f];
#pragma unroll
            for (int i = 0; i < 3; ++i) a1[i][nn] = x1_1[(n * 3 + i) * 128 + f];
#pragma unroll
            for (int i = 0; i < 5; ++i) a2[i][nn] = x1_2[(n * 5 + i) * 128 + f];
            c0[0][nn] = x2_0[n * 128 + f];
#pragma unroll
            for (int j = 0; j < 3; ++j) c1[j][nn] = x2_1[(n * 3 + j) * 128 + f];
#pragma unroll
            for (int j = 0; j < 5; ++j) c2[j][nn] = x2_2[(n * 5 + j) * 128 + f];
        }

        float y0v[1][2], y1v[3][2], y2v[5][2];
#pragma unroll
        for (int k = 0; k < 1; ++k) { y0v[k][0] = 0.f; y0v[k][1] = 0.f; }
#pragma unroll
        for (int k = 0; k < 3; ++k) { y1v[k][0] = 0.f; y1v[k][1] = 0.f; }
#pragma unroll
        for (int k = 0; k < 5; ++k) { y2v[k][0] = 0.f; y2v[k][1] = 0.f; }

        const int p0 = 2 * pass, p1 = 2 * pass + 1;
        triple_acc<1,1,1>(cg0,  a0, c0, cf[0][p0],  cf[0][p1],  y0v);  // (0,0,0)
        triple_acc<1,3,3>(cg1,  a0, c1, cf[1][p0],  cf[1][p1],  y1v);  // (0,1,1)
        triple_acc<1,5,5>(cg2,  a0, c2, cf[2][p0],  cf[2][p1],  y2v);  // (0,2,2)
        triple_acc<3,1,3>(cg3,  a1, c0, cf[3][p0],  cf[3][p1],  y1v);  // (1,0,1)
        triple_acc<3,3,1>(cg4,  a1, c1, cf[4][p0],  cf[4][p1],  y0v);  // (1,1,0)
        triple_acc<3,3,3>(cg5,  a1, c1, cf[5][p0],  cf[5][p1],  y1v);  // (1,1,1)
        triple_acc<3,3,5>(cg6,  a1, c1, cf[6][p0],  cf[6][p1],  y2v);  // (1,1,2)
        triple_acc<3,5,3>(cg7,  a1, c2, cf[7][p0],  cf[7][p1],  y1v);  // (1,2,1)
        triple_acc<3,5,5>(cg8,  a1, c2, cf[8][p0],  cf[8][p1],  y2v);  // (1,2,2)
        triple_acc<5,1,5>(cg9,  a2, c0, cf[9][p0],  cf[9][p1],  y2v);  // (2,0,2)
        triple_acc<5,3,3>(cg10, a2, c1, cf[10][p0], cf[10][p1], y1v);  // (2,1,1)
        triple_acc<5,3,5>(cg11, a2, c1, cf[11][p0], cf[11][p1], y2v);  // (2,1,2)
        triple_acc<5,5,1>(cg12, a2, c2, cf[12][p0], cf[12][p1], y0v);  // (2,2,0)
        triple_acc<5,5,3>(cg13, a2, c2, cf[13][p0], cf[13][p1], y1v);  // (2,2,1)
        triple_acc<5,5,5>(cg14, a2, c2, cf[14][p0], cf[14][p1], y2v);  // (2,2,2)

#pragma unroll
        for (int nn = 0; nn < 2; ++nn) {
            const int n = nb + nn;
            out[n * 128 + f] = y0v[0][nn];
#pragma unroll
            for (int k = 0; k < 3; ++k)
                out[Y1OFF + (n * 3 + k) * 128 + f] = y1v[k][nn];
#pragma unroll
            for (int k = 0; k < 5; ++k)
                out[Y2OFF + (n * 5 + k) * 128 + f] = y2v[k][nn];
        }
    }
}

extern "C" void kernel_launch(void* const* d_in, const int* in_sizes, int n_in,
                              void* d_out, int out_size, void* d_ws, size_t ws_size,
                              hipStream_t stream) {
    const float* x1_0 = (const float*)d_in[0];
    const float* x1_1 = (const float*)d_in[1];
    const float* x1_2 = (const float*)d_in[2];
    const float* x2_0 = (const float*)d_in[3];
    const float* x2_1 = (const float*)d_in[4];
    const float* x2_2 = (const float*)d_in[5];
    const float* rbf  = (const float*)d_in[6];
    // setup_inputs order: per triple, cg then W, interleaved
    const float* cg[15];
    const float* W[15];
    for (int t = 0; t < 15; ++t) {
        cg[t] = (const float*)d_in[7 + 2 * t];
        W[t]  = (const float*)d_in[8 + 2 * t];
    }
    float* out = (float*)d_out;

    dim3 grid(NPAIR / NB);   // 7500
    dim3 block(256);
    pair_mixing_kernel<<<grid, block, 0, stream>>>(
        x1_0, x1_1, x1_2, x2_0, x2_1, x2_2, rbf,
        cg[0], cg[1], cg[2], cg[3], cg[4], cg[5], cg[6], cg[7],
        cg[8], cg[9], cg[10], cg[11], cg[12], cg[13], cg[14],
        W[0], W[1], W[2], W[3], W[4], W[5], W[6], W[7],
        W[8], W[9], W[10], W[11], W[12], W[13], W[14],
        out);
}